// Round 6
// baseline (254.725 us; speedup 1.0000x reference)
//
#include <hip/hip_runtime.h>

// Attention, 20 slices of [N=1024, D=256]. R6: kill the V LDS round-trip.
// PV's B-operand (k=m contiguous) is loaded straight from global x as two
// float4 per fragment (x[d][m] is m-contiguous) -> LDS ops/wave-tile 38->16,
// LDS 37.3KB -> 3 blocks/CU, 2 barriers/tile (B3 gone). P tile uses padded
// pitch 68 shorts (legal: VALU-written, not DMA) -> conflict-light reads.
// S-phase/Kmd staging/epilogue/prep unchanged from R5 (verified correct).

typedef __attribute__((ext_vector_type(8))) short bf16x8;
typedef __attribute__((ext_vector_type(4))) float f32x4;
typedef __attribute__((ext_vector_type(16))) float f32x16;

#define GLD16(gp, lp) __builtin_amdgcn_global_load_lds( \
    (const __attribute__((address_space(1))) unsigned int*)(const void*)(gp), \
    (__attribute__((address_space(3))) unsigned int*)(void*)(lp), 16, 0, 0)

// LDS-only barrier: no vmcnt drain (keeps global loads / K-DMA in flight)
#define LDS_BARRIER() __asm__ volatile("s_waitcnt lgkmcnt(0)\ns_barrier" ::: "memory")

__device__ __forceinline__ unsigned int pack_bf16_rne(float a, float b) {
    unsigned int ua = __float_as_uint(a); ua += 0x7FFFu + ((ua >> 16) & 1u);
    unsigned int ub = __float_as_uint(b); ub += 0x7FFFu + ((ub >> 16) & 1u);
    return (ua >> 16) | (ub & 0xFFFF0000u);
}
__device__ __forceinline__ unsigned int pack2_trunc(float lo, float hi) {
    return __builtin_amdgcn_perm(__float_as_uint(hi), __float_as_uint(lo), 0x07060302u);
}

// XT[slice][n][d] bf16, 16B-chunk swizzle chunk ^= n&7 (unchanged from R5).
__global__ __launch_bounds__(256) void prep_kernel(const float* __restrict__ x,
                                                   unsigned short* __restrict__ XT) {
    int tid = blockIdx.x * 256 + threadIdx.x;   // [0, 81920)
    int slice = tid >> 12;
    int r = tid & 4095;
    int dcg = r >> 9;                 // 4-chunk group 0..7 (d0 = dcg*32)
    int n0 = (r & 511) * 2;
    const float* p = x + slice * 262144 + dcg * 32768 + n0;
    float2 L[32];
    #pragma unroll
    for (int j = 0; j < 32; ++j) L[j] = *(const float2*)(p + j * 1024);
    unsigned short* qb = XT + slice * 262144;
    #pragma unroll
    for (int i = 0; i < 2; ++i) {
        int n = n0 + i;
        unsigned short* row = qb + n * 256;
        #pragma unroll
        for (int c = 0; c < 4; ++c) {
            const float2* Lc = &L[c * 8];
            unsigned int w0, w1, w2, w3;
            if (i == 0) {
                w0 = pack_bf16_rne(Lc[0].x, Lc[1].x); w1 = pack_bf16_rne(Lc[2].x, Lc[3].x);
                w2 = pack_bf16_rne(Lc[4].x, Lc[5].x); w3 = pack_bf16_rne(Lc[6].x, Lc[7].x);
            } else {
                w0 = pack_bf16_rne(Lc[0].y, Lc[1].y); w1 = pack_bf16_rne(Lc[2].y, Lc[3].y);
                w2 = pack_bf16_rne(Lc[4].y, Lc[5].y); w3 = pack_bf16_rne(Lc[6].y, Lc[7].y);
            }
            *(uint4*)(row + (((dcg * 4 + c) ^ (n & 7)) * 8)) = make_uint4(w0, w1, w2, w3);
        }
    }
}

#define P_PITCH 68   // shorts per P row (pad 64->68: rotates bank-pairs per row)

__global__ __launch_bounds__(256, 3) void attn_kernel(const unsigned short* __restrict__ XT,
                                                      const float* __restrict__ x,
                                                      const int* __restrict__ beta,
                                                      float* __restrict__ out) {
    __shared__ __align__(16) unsigned short Kmd[64 * 256];   // 32KB K-tile [m][d]
    __shared__ __align__(16) unsigned short Pb[32 * P_PITCH];// 4.25KB P [n][m]
    __shared__ float Lpart[4 * 32];
    __shared__ float Ltot[32];

    int bid = blockIdx.x;
    int t = ((bid & 7) * 80) + (bid >> 3);      // XCD-locality swizzle (640 blocks)
    int slice = t >> 5, qh = t & 31;            // qh: 32-row q-tile index

    int tid = threadIdx.x;
    int lane = tid & 63, wv = tid >> 6;
    int nl = lane & 15, g = lane >> 4;          // 16x16 frame
    int lo = lane & 31, hi = lane >> 5;         // 32x32 frame

    const unsigned short* xt_s = XT + slice * 262144;
    const float* xs = x + slice * 262144;
    float cscale = (float)(beta[0]) * 1.44269504089f;   // beta * log2(e)

    // ---- Q fragments (2 strips of 16 n) + fixed softmax max per column ----
    bf16x8 qf[2][8];
    float mcol[2];
    #pragma unroll
    for (int nq = 0; nq < 2; ++nq) {
        int n = qh * 32 + nq * 16 + nl;
        const unsigned short* qrow = xt_s + n * 256;
        float dg = 0.f;
        #pragma unroll
        for (int ks = 0; ks < 8; ++ks) {
            qf[nq][ks] = *(const bf16x8*)(qrow + (((ks * 4 + g) ^ (n & 7)) * 8));
            const unsigned int* qu = (const unsigned int*)&qf[nq][ks];
            #pragma unroll
            for (int w = 0; w < 4; ++w) {
                float flo = __uint_as_float(qu[w] << 16);
                float fhi = __uint_as_float(qu[w] & 0xFFFF0000u);
                dg = fmaf(flo, flo, dg);
                dg = fmaf(fhi, fhi, dg);
            }
        }
        dg += __shfl_xor(dg, 16);
        dg += __shfl_xor(dg, 32);
        mcol[nq] = dg * cscale;
    }

    f32x16 acc[2];                   // O[32n x 64d]: wave owns d in [wv*64,+64)
    acc[0] = (f32x16)(0.f); acc[1] = (f32x16)(0.f);
    float lac0 = 0.f, lac1 = 0.f;

    // per-lane V row base: d = wv*64 + db*32 + lo, m-offset = hi*8
    const float* vbase0 = xs + (wv * 64 + lo) * 1024 + hi * 8;
    const float* vbase1 = vbase0 + 32 * 1024;

    // ---- prologue: stage K-tile 0 (DMA) ----
    #pragma unroll
    for (int i = 0; i < 8; ++i) {
        int ch = wv * 8 + i;
        GLD16(xt_s + ch * 512 + lane * 8, &Kmd[ch * 512]);
    }

    for (int kt = 0; kt < 16; ++kt) {
        __syncthreads();             // B1: K-tile kt DMA complete + visible

        // ---- V fragment loads for tile kt, d-block 0 (covered by S-phase) ----
        float4 vA[8];
        const float* vt0 = vbase0 + kt * 64;
        #pragma unroll
        for (int ks = 0; ks < 4; ++ks) {
            vA[ks * 2 + 0] = *(const float4*)(vt0 + ks * 16);
            vA[ks * 2 + 1] = *(const float4*)(vt0 + ks * 16 + 4);
        }

        // ---- S: wave's 16m sub-tile x both 16n strips (A-frag reused) ----
        f32x4 s0 = {0.f,0.f,0.f,0.f}, s1 = {0.f,0.f,0.f,0.f};
        #pragma unroll
        for (int ks = 0; ks < 8; ++ks) {
            bf16x8 af = *(const bf16x8*)(&Kmd[(wv * 16 + nl) * 256 + (((ks * 4 + g) ^ (nl & 7)) * 8)]);
            s0 = __builtin_amdgcn_mfma_f32_16x16x32_bf16(af, qf[0][ks], s0, 0, 0, 0);
            s1 = __builtin_amdgcn_mfma_f32_16x16x32_bf16(af, qf[1][ks], s1, 0, 0, 0);
        }

        // ---- V loads, d-block 1 ----
        float4 vB[8];
        const float* vt1 = vbase1 + kt * 64;
        #pragma unroll
        for (int ks = 0; ks < 4; ++ks) {
            vB[ks * 2 + 0] = *(const float4*)(vt1 + ks * 16);
            vB[ks * 2 + 1] = *(const float4*)(vt1 + ks * 16 + 4);
        }

        // ---- softmax (fixed max) + P writes; row pitch 68 shorts ----
        {
            float p0 = exp2f(fmaf(s0[0], cscale, -mcol[0]));
            float p1 = exp2f(fmaf(s0[1], cscale, -mcol[0]));
            float p2 = exp2f(fmaf(s0[2], cscale, -mcol[0]));
            float p3 = exp2f(fmaf(s0[3], cscale, -mcol[0]));
            lac0 += (p0 + p1) + (p2 + p3);
            *(uint2*)(&Pb[nl * P_PITCH + (((wv * 4 + g) ^ nl) * 4)]) =
                make_uint2(pack2_trunc(p0, p1), pack2_trunc(p2, p3));
        }
        {
            float p0 = exp2f(fmaf(s1[0], cscale, -mcol[1]));
            float p1 = exp2f(fmaf(s1[1], cscale, -mcol[1]));
            float p2 = exp2f(fmaf(s1[2], cscale, -mcol[1]));
            float p3 = exp2f(fmaf(s1[3], cscale, -mcol[1]));
            lac1 += (p0 + p1) + (p2 + p3);
            *(uint2*)(&Pb[(16 + nl) * P_PITCH + (((wv * 4 + g) ^ nl) * 4)]) =
                make_uint2(pack2_trunc(p0, p1), pack2_trunc(p2, p3));
        }

        LDS_BARRIER();               // B2: P visible; all Kmd reads retired

        // restage Kmd for kt+1 (DMA in flight across PV, drained at next B1)
        if (kt < 15) {
            const unsigned short* gk = xt_s + (kt + 1) * 16384;
            #pragma unroll
            for (int i = 0; i < 8; ++i) {
                int ch = wv * 8 + i;
                GLD16(gk + ch * 512 + lane * 8, &Kmd[ch * 512]);
            }
        }

        // ---- PV: O[32n x 64d] += P[32n x 64m] * V[64m x 64d], 32x32x16 ----
        // A = P from LDS (2x b64 per frag, 2-way-free banking);
        // B = V packed from the global-loaded registers.
        #pragma unroll
        for (int ks = 0; ks < 4; ++ks) {
            union { bf16x8 v; uint2 u2[2]; } pf;
            pf.u2[0] = *(const uint2*)(&Pb[lo * P_PITCH + (((ks * 4 + hi * 2 + 0) ^ (lo & 15)) * 4)]);
            pf.u2[1] = *(const uint2*)(&Pb[lo * P_PITCH + (((ks * 4 + hi * 2 + 1) ^ (lo & 15)) * 4)]);
            union { bf16x8 v; unsigned int u[4]; } vf0, vf1;
            vf0.u[0] = pack2_trunc(vA[ks*2+0].x, vA[ks*2+0].y);
            vf0.u[1] = pack2_trunc(vA[ks*2+0].z, vA[ks*2+0].w);
            vf0.u[2] = pack2_trunc(vA[ks*2+1].x, vA[ks*2+1].y);
            vf0.u[3] = pack2_trunc(vA[ks*2+1].z, vA[ks*2+1].w);
            vf1.u[0] = pack2_trunc(vB[ks*2+0].x, vB[ks*2+0].y);
            vf1.u[1] = pack2_trunc(vB[ks*2+0].z, vB[ks*2+0].w);
            vf1.u[2] = pack2_trunc(vB[ks*2+1].x, vB[ks*2+1].y);
            vf1.u[3] = pack2_trunc(vB[ks*2+1].z, vB[ks*2+1].w);
            acc[0] = __builtin_amdgcn_mfma_f32_32x32x16_bf16(pf.v, vf0.v, acc[0], 0, 0, 0);
            acc[1] = __builtin_amdgcn_mfma_f32_32x32x16_bf16(pf.v, vf1.v, acc[1], 0, 0, 0);
        }
    }

    // ---- epilogue: softmax denominators, scale, store ----
    lac0 += __shfl_xor(lac0, 16); lac0 += __shfl_xor(lac0, 32);
    lac1 += __shfl_xor(lac1, 16); lac1 += __shfl_xor(lac1, 32);
    if (lane < 16) {
        Lpart[wv * 32 + nl] = lac0;
        Lpart[wv * 32 + 16 + nl] = lac1;
    }
    LDS_BARRIER();
    if (tid < 32)
        Ltot[tid] = 1.f / (Lpart[tid] + Lpart[32 + tid] + Lpart[64 + tid] + Lpart[96 + tid]);
    LDS_BARRIER();

    float* outs = out + slice * 262144 + (qh * 32) * 256;
    #pragma unroll
    for (int rq = 0; rq < 4; ++rq) {
        f32x4 li = *(const f32x4*)(&Ltot[rq * 8 + hi * 4]);
        #pragma unroll
        for (int j = 0; j < 4; ++j) {
            int nloc = rq * 8 + hi * 4 + j;
            #pragma unroll
            for (int db = 0; db < 2; ++db)
                outs[nloc * 256 + wv * 64 + db * 32 + lo] = acc[db][rq * 4 + j] * li[j];
        }
    }
}

extern "C" void kernel_launch(void* const* d_in, const int* in_sizes, int n_in,
                              void* d_out, int out_size, void* d_ws, size_t ws_size,
                              hipStream_t stream) {
    const float* x = (const float*)d_in[0];
    const int* beta = (const int*)d_in[1];
    float* out = (float*)d_out;
    unsigned short* XT = (unsigned short*)d_ws;   // 10,485,760 bytes total ws use
    prep_kernel<<<320, 256, 0, stream>>>(x, XT);
    attn_kernel<<<640, 256, 0, stream>>>(XT, x, beta, out);
}

// Round 7
// 162.482 us; speedup vs baseline: 1.5677x; 1.5677x over previous
//
#include <hip/hip_runtime.h>

// Attention, 20 slices of [N=1024, D=256]. R7: pipelined wave-autonomous loop.
// - K operand: global XT -> registers (kf), no LDS, no DMA, no vmcnt drain.
//   Per-instr pattern = 16 rows x one full 64B line each (XOR swizzle keeps the
//   4 chunks inside one 64B group) -> perfectly coalesced, L1-reused across ks.
// - V: R5's verified fp32->bf16 reg->LDS transpose, but wave-private (each wave
//   stages exactly the 64-d slab its PV reads) and double-buffered by tile
//   parity into the m-dimension of Vb[d][64] -> no barrier dependency.
// - P: double-buffered Pb[2][32][40] -> ONE lgkm-only barrier per tile.
// - S(kt+1) and PV(kt) sit in the same inter-barrier region: independent MFMA
//   chains interleave (the phase-level pipelining R4-R6 lacked).
// - All LDS patterns audited: Vb write 4-touch/bank uniform, Vb read
//   8-touch/bank uniform (conflict-free b128), Pb read uniform via pitch 40.

typedef __attribute__((ext_vector_type(8))) short bf16x8;
typedef __attribute__((ext_vector_type(4))) float f32x4;
typedef __attribute__((ext_vector_type(16))) float f32x16;

// LDS-only barrier: no vmcnt drain (global kf/vreg loads stay in flight)
#define LDS_BARRIER() __asm__ volatile("s_waitcnt lgkmcnt(0)\ns_barrier" ::: "memory")

__device__ __forceinline__ unsigned int pack_bf16_rne(float a, float b) {
    unsigned int ua = __float_as_uint(a); ua += 0x7FFFu + ((ua >> 16) & 1u);
    unsigned int ub = __float_as_uint(b); ub += 0x7FFFu + ((ub >> 16) & 1u);
    return (ua >> 16) | (ub & 0xFFFF0000u);
}
__device__ __forceinline__ unsigned int pack2_trunc(float lo, float hi) {
    return __builtin_amdgcn_perm(__float_as_uint(hi), __float_as_uint(lo), 0x07060302u);
}

// XT[slice][n][d] bf16, 16B-chunk swizzle chunk ^= n&7 (verified since R2).
__global__ __launch_bounds__(256) void prep_kernel(const float* __restrict__ x,
                                                   unsigned short* __restrict__ XT) {
    int tid = blockIdx.x * 256 + threadIdx.x;   // [0, 81920)
    int slice = tid >> 12;
    int r = tid & 4095;
    int dcg = r >> 9;                 // 4-chunk group 0..7 (d0 = dcg*32)
    int n0 = (r & 511) * 2;
    const float* p = x + slice * 262144 + dcg * 32768 + n0;
    float2 L[32];
    #pragma unroll
    for (int j = 0; j < 32; ++j) L[j] = *(const float2*)(p + j * 1024);
    unsigned short* qb = XT + slice * 262144;
    #pragma unroll
    for (int i = 0; i < 2; ++i) {
        int n = n0 + i;
        unsigned short* row = qb + n * 256;
        #pragma unroll
        for (int c = 0; c < 4; ++c) {
            const float2* Lc = &L[c * 8];
            unsigned int w0, w1, w2, w3;
            if (i == 0) {
                w0 = pack_bf16_rne(Lc[0].x, Lc[1].x); w1 = pack_bf16_rne(Lc[2].x, Lc[3].x);
                w2 = pack_bf16_rne(Lc[4].x, Lc[5].x); w3 = pack_bf16_rne(Lc[6].x, Lc[7].x);
            } else {
                w0 = pack_bf16_rne(Lc[0].y, Lc[1].y); w1 = pack_bf16_rne(Lc[2].y, Lc[3].y);
                w2 = pack_bf16_rne(Lc[4].y, Lc[5].y); w3 = pack_bf16_rne(Lc[6].y, Lc[7].y);
            }
            *(uint4*)(row + (((dcg * 4 + c) ^ (n & 7)) * 8)) = make_uint4(w0, w1, w2, w3);
        }
    }
}

#define P_PITCH 40   // shorts per P row: 80B, 16B-aligned, uniform bank spread

__global__ __launch_bounds__(256) void attn_kernel(const unsigned short* __restrict__ XT,
                                                   const float* __restrict__ x,
                                                   const int* __restrict__ beta,
                                                   float* __restrict__ out) {
    __shared__ __align__(16) unsigned short Vb[256 * 64];    // 32KB [d][2 halves x 32m]
    __shared__ __align__(16) unsigned short Pb[2][32 * P_PITCH]; // 5.1KB
    __shared__ float Lpart[64];
    __shared__ float Ltot[32];

    int bid = blockIdx.x;
    int t = ((bid & 7) * 80) + (bid >> 3);      // XCD-locality swizzle
    int slice = t >> 5, nh = t & 31;            // nh: 32-row q-tile index

    int tid = threadIdx.x;
    int lane = tid & 63, wv = tid >> 6;
    int nl = lane & 15, g = (lane >> 4) & 3;    // 16x16 frame
    int lo = lane & 31, g8 = lane >> 5;         // 32x32 frame
    int r8 = lane >> 3, c8 = lane & 7;          // V-staging frame (d&7 == r8)
    int ns = wv >> 1, ms = wv & 1;              // n-strip / m-sub roles

    const unsigned short* xt_s = XT + slice * 262144;
    const float* xs = x + slice * 262144;
    float cscale = (float)(beta[0]) * 1.44269504089f;   // beta * log2(e)

    // ---- Q fragments (one 16-n strip) + fixed softmax max per column ----
    bf16x8 qf[8];
    float mcol;
    {
        const unsigned short* qrow = xt_s + (nh * 32 + ns * 16 + nl) * 256;
        float dg = 0.f;
        #pragma unroll
        for (int ks = 0; ks < 8; ++ks) {
            qf[ks] = *(const bf16x8*)(qrow + (((ks * 4 + g) ^ (nl & 7)) * 8));
            const unsigned int* qu = (const unsigned int*)&qf[ks];
            #pragma unroll
            for (int w = 0; w < 4; ++w) {
                float flo = __uint_as_float(qu[w] << 16);
                float fhi = __uint_as_float(qu[w] & 0xFFFF0000u);
                dg = fmaf(flo, flo, dg);
                dg = fmaf(fhi, fhi, dg);
            }
        }
        dg += __shfl_xor(dg, 16);
        dg += __shfl_xor(dg, 32);
        mcol = dg * cscale;
    }

    f32x16 acc[2];                   // O[32n x 64d]: wave owns d in [wv*64,+64)
    acc[0] = (f32x16)(0.f); acc[1] = (f32x16)(0.f);
    float lac = 0.f;

    bf16x8 kf[8];
    float4 vreg[8];

    // ---- prologue: tile 0 -> kf, vreg, S(0), P(0)/V(0) writes ----
    {
        const unsigned short* krow = xt_s + (ms * 16 + nl) * 256;
        #pragma unroll
        for (int ks = 0; ks < 8; ++ks)
            kf[ks] = *(const bf16x8*)(krow + (((ks * 4 + g) ^ (nl & 7)) * 8));
        #pragma unroll
        for (int i = 0; i < 8; ++i)
            vreg[i] = *(const float4*)(xs + (wv * 64 + i * 8 + r8) * 1024 + c8 * 4);

        f32x4 st = {0.f, 0.f, 0.f, 0.f};
        #pragma unroll
        for (int ks = 0; ks < 8; ++ks)
            st = __builtin_amdgcn_mfma_f32_16x16x32_bf16(kf[ks], qf[ks], st, 0, 0, 0);
        float p0 = exp2f(fmaf(st[0], cscale, -mcol));
        float p1 = exp2f(fmaf(st[1], cscale, -mcol));
        float p2 = exp2f(fmaf(st[2], cscale, -mcol));
        float p3 = exp2f(fmaf(st[3], cscale, -mcol));
        lac += (p0 + p1) + (p2 + p3);
        *(uint2*)(&Pb[0][(ns * 16 + nl) * P_PITCH + ms * 16 + g * 4]) =
            make_uint2(pack2_trunc(p0, p1), pack2_trunc(p2, p3));
        #pragma unroll
        for (int i = 0; i < 8; ++i) {
            int d = wv * 64 + i * 8 + r8;
            *(uint2*)(&Vb[d * 64 + (((c8 >> 1) ^ r8) * 8) + (c8 & 1) * 4]) =
                make_uint2(pack2_trunc(vreg[i].x, vreg[i].y), pack2_trunc(vreg[i].z, vreg[i].w));
        }
    }

    for (int kt = 0; kt < 32; ++kt) {
        LDS_BARRIER();               // Pb[kt&1] (+ own Vb half) visible; prev PV retired
        int cur = kt & 1;
        bool more = kt < 31;

        // global loads for tile kt+1 (in flight across the whole region)
        if (more) {
            const unsigned short* krow = xt_s + ((kt + 1) * 32 + ms * 16 + nl) * 256;
            #pragma unroll
            for (int ks = 0; ks < 8; ++ks)
                kf[ks] = *(const bf16x8*)(krow + (((ks * 4 + g) ^ (nl & 7)) * 8));
            const float* gv = xs + (kt + 1) * 32;
            #pragma unroll
            for (int i = 0; i < 8; ++i)
                vreg[i] = *(const float4*)(gv + (wv * 64 + i * 8 + r8) * 1024 + c8 * 4);
        }

        // ---- PV(kt): O[32n x 64d] += P[32n x 32m] V[32m x 64d], 32x32x16 ----
        #pragma unroll
        for (int kstep = 0; kstep < 2; ++kstep) {
            bf16x8 pf = *(const bf16x8*)(&Pb[cur][lo * P_PITCH + kstep * 16 + g8 * 8]);
            #pragma unroll
            for (int db = 0; db < 2; ++db) {
                int d = wv * 64 + db * 32 + lo;
                bf16x8 vf = *(const bf16x8*)(&Vb[d * 64 + (((cur * 4 + kstep * 2 + g8) ^ (lo & 7)) * 8)]);
                acc[db] = __builtin_amdgcn_mfma_f32_32x32x16_bf16(pf, vf, acc[db], 0, 0, 0);
            }
        }

        // ---- S(kt+1) + softmax + P/V writes into the other buffers ----
        if (more) {
            f32x4 st = {0.f, 0.f, 0.f, 0.f};
            #pragma unroll
            for (int ks = 0; ks < 8; ++ks)
                st = __builtin_amdgcn_mfma_f32_16x16x32_bf16(kf[ks], qf[ks], st, 0, 0, 0);
            float p0 = exp2f(fmaf(st[0], cscale, -mcol));
            float p1 = exp2f(fmaf(st[1], cscale, -mcol));
            float p2 = exp2f(fmaf(st[2], cscale, -mcol));
            float p3 = exp2f(fmaf(st[3], cscale, -mcol));
            lac += (p0 + p1) + (p2 + p3);
            int nxt = cur ^ 1;
            *(uint2*)(&Pb[nxt][(ns * 16 + nl) * P_PITCH + ms * 16 + g * 4]) =
                make_uint2(pack2_trunc(p0, p1), pack2_trunc(p2, p3));
            #pragma unroll
            for (int i = 0; i < 8; ++i) {
                int d = wv * 64 + i * 8 + r8;
                *(uint2*)(&Vb[d * 64 + (((nxt * 4 + (c8 >> 1)) ^ r8) * 8) + (c8 & 1) * 4]) =
                    make_uint2(pack2_trunc(vreg[i].x, vreg[i].y), pack2_trunc(vreg[i].z, vreg[i].w));
            }
        }
    }

    // ---- epilogue: combine l over the 2 m-sub waves per strip, scale, store ----
    lac += __shfl_xor(lac, 16);
    lac += __shfl_xor(lac, 32);
    if (lane < 16) Lpart[wv * 16 + nl] = lac;
    LDS_BARRIER();
    if (tid < 32)
        Ltot[tid] = 1.f / (Lpart[(tid >> 4) * 32 + (tid & 15)] +
                           Lpart[(tid >> 4) * 32 + 16 + (tid & 15)]);
    LDS_BARRIER();

    float* outs = out + slice * 262144 + (nh * 32) * 256;
    #pragma unroll
    for (int rq = 0; rq < 4; ++rq) {
        f32x4 li = *(const f32x4*)(&Ltot[rq * 8 + g8 * 4]);
        #pragma unroll
        for (int j = 0; j < 4; ++j) {
            int nloc = rq * 8 + g8 * 4 + j;
            #pragma unroll
            for (int db = 0; db < 2; ++db)
                outs[nloc * 256 + wv * 64 + db * 32 + lo] = acc[db][rq * 4 + j] * li[j];
        }
    }
}

extern "C" void kernel_launch(void* const* d_in, const int* in_sizes, int n_in,
                              void* d_out, int out_size, void* d_ws, size_t ws_size,
                              hipStream_t stream) {
    const float* x = (const float*)d_in[0];
    const int* beta = (const int*)d_in[1];
    float* out = (float*)d_out;
    unsigned short* XT = (unsigned short*)d_ws;   // 10,485,760 bytes total ws use
    prep_kernel<<<320, 256, 0, stream>>>(x, XT);
    attn_kernel<<<640, 256, 0, stream>>>(XT, x, beta, out);
}